// Round 1
// baseline (128.336 us; speedup 1.0000x reference)
//
#include <hip/hip_runtime.h>
#include <hip/hip_bf16.h>
#include <math.h>

typedef unsigned short u16;
typedef short short8 __attribute__((ext_vector_type(8)));
typedef float f32x4 __attribute__((ext_vector_type(4)));

// ---- ws layout (float offsets), FB = 524288 ----
// [0, 262144)        : PO[b][o][g] fp32
// [262144, 524288)   : Y[b][i][g] fp32
// FB+1280 .. +1288   : V fp32                  (k12 LSTM blocks)
// FB+1288 .. +1800   : hn fp32
// FB+1800 .. +2312   : cn fp32
// FB+2320 .. +4368   : C1PO[b][o] = sum_g wa'*PO
// FB+4368 .. +6416   : C2[b][i]   = sum_g wa'*Y
// FB+26896.. +27920  : S[b][g] = s2.Wa1 + ba1
// FB+27920.. +27928  : C1S[b] = sum_g wa'*S + ba2
#define FB    524288
#define SOFF  26896
#define C1S   27920

__device__ __forceinline__ u16 f2b(float x) { __hip_bfloat16 b = __float2bfloat16(x); return *(u16*)&b; }
__device__ __forceinline__ float dot4(const float4 a, const float4 b) {
    return a.x*b.x + a.y*b.y + a.z*b.z + a.w*b.w;
}

// ============================================================================
// K12: blocks 0..255 = PO/Y tiles via MFMA (+C1PO/C2 reduces);
//      blocks 256..263 = mean + LSTM + V head + S[b][g] + C1S[b].
// grid(264), block(256). Depends only on inputs.
// ============================================================================
__global__ __launch_bounds__(256) void k12_main(
    const float* __restrict__ ope, const float* __restrict__ ins,
    const float* __restrict__ hin, const float* __restrict__ cin,
    const float* __restrict__ W_ih, const float* __restrict__ W_hh,
    const float* __restrict__ b_ih, const float* __restrict__ b_hh,
    const float* __restrict__ Wv0, const float* __restrict__ bv0,
    const float* __restrict__ Wv1, const float* __restrict__ bv1,
    const float* __restrict__ Wv2, const float* __restrict__ bv2,
    const float* __restrict__ Wa0, const float* __restrict__ ba0,
    const float* __restrict__ Wa1, const float* __restrict__ ba1,
    const float* __restrict__ Wa2, const float* __restrict__ ba2,
    float* __restrict__ ws)
{
    __shared__ __align__(16) u16 Wa1s[128*136];   // bf16 Wa1 [g][h], pitch 136
    __shared__ __align__(16) u16 Wsel[128*72];    // bf16 Wo/Wi [h][d], pitch 72
    __shared__ __align__(16) u16 inrows[16*72];   // bf16 input rows, pitch 72
    __shared__ __align__(16) u16 Pb[16*136];      // bf16 P [m][h], pitch 136
    __shared__ float partb[64];
    const int t = threadIdx.x;

    if (blockIdx.x < 256) {
        // ---------------- PO / Y tile ----------------
        const int b = blockIdx.x >> 5;
        const int r0 = (blockIdx.x & 31) * 16;
        const int side = (r0 >= 256) ? 1 : 0;

        // stage Wa1 fp32 -> LDS bf16 [128][136]
        #pragma unroll
        for (int k = 0; k < 16; ++k) {
            const int e4 = t + k*256;
            const int g = e4 >> 5, hq = (e4 & 31) * 4;
            const float4 w = *(const float4*)(Wa1 + g*128 + hq);
            ushort4 u; u.x = f2b(w.x); u.y = f2b(w.y); u.z = f2b(w.z); u.w = f2b(w.w);
            *(ushort4*)&Wa1s[g*136 + hq] = u;
        }
        // stage Wo/Wi fp32 -> LDS bf16 [128][72]
        #pragma unroll
        for (int k = 0; k < 8; ++k) {
            const int e4 = t + k*256;
            const int h = e4 >> 4, dq = (e4 & 15) * 4;
            const float4 w = *(const float4*)(Wa0 + h*192 + 64 + side*64 + dq);
            ushort4 u; u.x = f2b(w.x); u.y = f2b(w.y); u.z = f2b(w.z); u.w = f2b(w.w);
            *(ushort4*)&Wsel[h*72 + dq] = u;
        }
        // stage 16 input rows -> LDS bf16 [16][72]
        {
            const int r = t >> 4, dq = (t & 15) * 4;
            const float* src = side
                ? (ins + b*16384 + (r0 - 256 + r)*64 + dq)
                : (ope + b*16512 + (1 + r0 + r)*64 + dq);
            const float4 w = *(const float4*)src;
            ushort4 u; u.x = f2b(w.x); u.y = f2b(w.y); u.z = f2b(w.z); u.w = f2b(w.w);
            *(ushort4*)&inrows[r*72 + dq] = u;
        }
        __syncthreads();

        const int lane = t & 63;
        const int wv   = t >> 6;            // 4 waves
        const int lrow = lane & 15;         // m (A) / n (B,D) selector
        const int grp  = lane >> 4;         // k-group
        const int lk   = grp * 8;           // k-base within 32

        // ---- phase 1: P[16][128] = IN(16x64) . Wsel^T ----
        const short8 a0 = *(const short8*)&inrows[lrow*72 + lk];
        const short8 a1 = *(const short8*)&inrows[lrow*72 + 32 + lk];
        #pragma unroll
        for (int nt = 0; nt < 2; ++nt) {
            const int h0 = (wv*2 + nt) * 16;
            const short8 b0 = *(const short8*)&Wsel[(h0 + lrow)*72 + lk];
            const short8 b1 = *(const short8*)&Wsel[(h0 + lrow)*72 + 32 + lk];
            f32x4 acc = {0.f, 0.f, 0.f, 0.f};
            acc = __builtin_amdgcn_mfma_f32_16x16x32_bf16(a0, b0, acc, 0, 0, 0);
            acc = __builtin_amdgcn_mfma_f32_16x16x32_bf16(a1, b1, acc, 0, 0, 0);
            // D: lane holds P[m=4*grp+r][h0+lrow]
            #pragma unroll
            for (int r = 0; r < 4; ++r)
                Pb[(4*grp + r)*136 + h0 + lrow] = f2b(acc[r]);
        }
        __syncthreads();

        // ---- phase 2: OUT[16][128] = P(16x128) . Wa1^T; fused 0.505 reduce ----
        short8 pa[4];
        #pragma unroll
        for (int ks = 0; ks < 4; ++ks)
            pa[ks] = *(const short8*)&Pb[lrow*136 + ks*32 + lk];

        const int rowbase = b*256 + r0 - side*256;
        float* dst = side ? (ws + 262144) : ws;
        float part[4] = {0.f, 0.f, 0.f, 0.f};
        #pragma unroll
        for (int nt = 0; nt < 2; ++nt) {
            const int g0 = (wv*2 + nt) * 16;
            f32x4 acc = {0.f, 0.f, 0.f, 0.f};
            #pragma unroll
            for (int ks = 0; ks < 4; ++ks) {
                const short8 bb = *(const short8*)&Wa1s[(g0 + lrow)*136 + ks*32 + lk];
                acc = __builtin_amdgcn_mfma_f32_16x16x32_bf16(pa[ks], bb, acc, 0, 0, 0);
            }
            const float wa = 0.505f * Wa2[g0 + lrow];
            #pragma unroll
            for (int r = 0; r < 4; ++r) {
                const int m = 4*grp + r;
                dst[(rowbase + m)*128 + g0 + lrow] = acc[r];
                part[r] = fmaf(wa, acc[r], part[r]);
            }
        }
        // butterfly over lrow bits -> sum over this wave's 32 g
        #pragma unroll
        for (int r = 0; r < 4; ++r) {
            float p = part[r];
            p += __shfl_xor(p, 1);
            p += __shfl_xor(p, 2);
            p += __shfl_xor(p, 4);
            p += __shfl_xor(p, 8);
            part[r] = p;
        }
        if (lrow == 0) {
            #pragma unroll
            for (int r = 0; r < 4; ++r)
                partb[wv*16 + grp*4 + r] = part[r];
        }
        __syncthreads();
        if (t < 16) {
            const float p = partb[t] + partb[16 + t] + partb[32 + t] + partb[48 + t];
            const int row = rowbase + t;
            if (!side) ws[FB + 2320 + row] = p;          // C1PO
            else       ws[FB + 4368 + row] = p;          // C2
        }
    } else {
        // ---------------- mean + LSTM + V head + S + C1S (block b) ----------
        const int b = blockIdx.x - 256;
        float* f = (float*)Wa1s;     // alias LDS
        float* state = f;            // 64
        float* hvec  = f + 64;       // 64
        float* gl    = f + 128;      // 256
        float* hn_s  = f + 384;      // 64
        float* t0a   = f + 448;      // 128
        float* t1a   = f + 576;      // 128
        float* s2s   = f + 704;      // 128
        float* red   = f + 832;      // 128 (S reduce)
        float* red4  = f + 1024;     // 1024 (mean partials, float4 granularity)

        // mean over rows 1..256 of ope[b]: float4 loads, 16 rows/thread
        {
            const int dq = (t & 15) * 4;
            const int q  = t >> 4;                         // 0..15
            const float* p = ope + b*16512 + (1 + q)*64 + dq;
            float4 s = make_float4(0.f, 0.f, 0.f, 0.f);
            #pragma unroll
            for (int r = 0; r < 16; ++r) {
                const float4 v = *(const float4*)(p + r*1024);  // rows q + 16r
                s.x += v.x; s.y += v.y; s.z += v.z; s.w += v.w;
            }
            *(float4*)&red4[(q*16 + (t & 15))*4] = s;
        }
        __syncthreads();
        if (t < 64) {
            float s = 0.f;
            #pragma unroll
            for (int q = 0; q < 16; ++q)
                s += red4[(q*16 + (t >> 2))*4 + (t & 3)];
            state[t] = s * (1.f/256.f);
        } else if (t < 128) hvec[t-64] = hin[b*64 + (t-64)];
        __syncthreads();

        {
            float g = b_ih[t] + b_hh[t];
            const float4* wi = (const float4*)(W_ih + t*64);
            const float4* wh = (const float4*)(W_hh + t*64);
            #pragma unroll
            for (int k = 0; k < 16; ++k)
                g += dot4(wi[k], *(const float4*)&state[k*4])
                   + dot4(wh[k], *(const float4*)&hvec[k*4]);
            gl[t] = g;
        }
        __syncthreads();

        if (t < 64) {
            const float ig = gl[t], fg = gl[64+t], gg = gl[128+t], og = gl[192+t];
            const float c  = cin[b*64 + t];
            const float si = 1.f/(1.f + expf(-ig));
            const float sf = 1.f/(1.f + expf(-fg));
            const float so = 1.f/(1.f + expf(-og));
            const float cn = sf*c + si*tanhf(gg);
            const float hn = so*tanhf(cn);
            ws[FB + 1288 + b*64 + t] = hn;
            ws[FB + 1800 + b*64 + t] = cn;
            hn_s[t] = hn;
        }
        __syncthreads();

        if (t < 128) {
            float a = bv0[t];
            const float4* w = (const float4*)(Wv0 + t*64);
            #pragma unroll
            for (int k = 0; k < 16; ++k) a += dot4(w[k], *(const float4*)&hn_s[k*4]);
            t0a[t] = a;
        }
        __syncthreads();
        if (t < 128) {
            float a = bv1[t];
            const float4* w = (const float4*)(Wv1 + t*128);
            #pragma unroll
            for (int k = 0; k < 32; ++k) a += dot4(w[k], *(const float4*)&t0a[k*4]);
            a = (a >= 0.f) ? a : 0.01f*a;
            t1a[t] = a * Wv2[t];
            float s2 = ba0[t];
            const float4* w0 = (const float4*)(Wa0 + t*192);
            #pragma unroll
            for (int k = 0; k < 16; ++k) s2 += dot4(w0[k], *(const float4*)&hn_s[k*4]);
            s2s[t] = s2;
        }
        __syncthreads();
        if (t < 128) {
            // S[b][g] = s2 . Wa1[g] + ba1[g]   (fp32 Wa1)
            float sv = ba1[t];
            const float4* w = (const float4*)(Wa1 + t*128);
            #pragma unroll
            for (int k = 0; k < 32; ++k) sv += dot4(w[k], *(const float4*)&s2s[k*4]);
            ws[FB + SOFF + b*128 + t] = sv;
            red[t] = 0.505f * Wa2[t] * sv;          // wa' * S
        }
        __syncthreads();
        if (t < 64) {
            float c = red[t] + red[t + 64];
            float v = t1a[t] + t1a[t + 64];
            c += __shfl_xor(c, 32); v += __shfl_xor(v, 32);
            c += __shfl_xor(c, 16); v += __shfl_xor(v, 16);
            c += __shfl_xor(c, 8);  v += __shfl_xor(v, 8);
            c += __shfl_xor(c, 4);  v += __shfl_xor(v, 4);
            c += __shfl_xor(c, 2);  v += __shfl_xor(v, 2);
            c += __shfl_xor(c, 1);  v += __shfl_xor(v, 1);
            if (t == 0) {
                ws[FB + C1S + b]  = c + ba2[0];
                ws[FB + 1280 + b] = v + bv2[0];
            }
        }
    }
}

// ============================================================================
// K3: A[b][o][i] = C1PO[b,o] + C1S[b] + C2[b,i] + sum_g wb'[g]*|PO + S + Y|,
// wb' = 0.495*Wa2. grid(1024), block(256): blk = (b, o-tile of 4, i-half);
// threads = 128 i x 2 gc-halves, combined via LDS. Block 0 emits V/hn/cn.
// ============================================================================
__global__ __launch_bounds__(256) void k3_adv(const float* __restrict__ ws,
                                              const float* __restrict__ Wa2,
                                              float* __restrict__ out)
{
    __shared__ __align__(16) float cmb[128*4];
    const int t = threadIdx.x;
    const int blk = blockIdx.x;
    const int b  = blk >> 7;
    const int o0 = ((blk >> 1) & 63) * 4;
    const int ih = blk & 1;
    const int gh = t >> 7;               // gc half: 0 -> gc 0..3, 1 -> gc 4..7
    const int li = t & 127;
    const int i  = ih * 128 + li;

    float acc[4] = {0.f, 0.f, 0.f, 0.f};
    #pragma unroll
    for (int gc2 = 0; gc2 < 4; ++gc2) {
        const int gc = gh*4 + gc2;
        float syv[16], wv[16];
        {
            const float* yr = ws + 262144 + (b*256 + i)*128 + gc*16;
            const float* sr = ws + FB + SOFF + b*128 + gc*16;    // uniform
            const float* wr = Wa2 + gc*16;                       // uniform
            #pragma unroll
            for (int k = 0; k < 4; ++k) {
                const float4 y4 = *(const float4*)(yr + k*4);
                const float4 s4 = *(const float4*)(sr + k*4);
                const float4 w4 = *(const float4*)(wr + k*4);
                syv[k*4+0] = y4.x + s4.x; syv[k*4+1] = y4.y + s4.y;
                syv[k*4+2] = y4.z + s4.z; syv[k*4+3] = y4.w + s4.w;
                wv[k*4+0] = 0.495f*w4.x; wv[k*4+1] = 0.495f*w4.y;
                wv[k*4+2] = 0.495f*w4.z; wv[k*4+3] = 0.495f*w4.w;
            }
        }
        #pragma unroll
        for (int o = 0; o < 4; ++o) {
            const float* xr = ws + (b*256 + o0 + o)*128 + gc*16;   // uniform
            float a = acc[o];
            #pragma unroll
            for (int k = 0; k < 4; ++k) {
                const float4 x4 = *(const float4*)(xr + k*4);
                a = fmaf(wv[k*4+0], fabsf(x4.x + syv[k*4+0]), a);
                a = fmaf(wv[k*4+1], fabsf(x4.y + syv[k*4+1]), a);
                a = fmaf(wv[k*4+2], fabsf(x4.z + syv[k*4+2]), a);
                a = fmaf(wv[k*4+3], fabsf(x4.w + syv[k*4+3]), a);
            }
            acc[o] = a;
        }
    }
    if (gh) *(float4*)&cmb[li*4] = make_float4(acc[0], acc[1], acc[2], acc[3]);
    __syncthreads();
    if (!gh) {
        const float4 c4 = *(const float4*)&cmb[li*4];
        acc[0] += c4.x; acc[1] += c4.y; acc[2] += c4.z; acc[3] += c4.w;
        const float c2  = ws[FB + 4368 + b*256 + i];
        const float c1s = ws[FB + C1S + b];
        #pragma unroll
        for (int o = 0; o < 4; ++o)
            out[8 + b*65536 + (o0 + o)*256 + i] =
                ws[FB + 2320 + b*256 + o0 + o] + c1s + c2 + acc[o];
    }

    if (blk == 0) {
        if (t < 8) out[t] = ws[FB + 1280 + t];              // V fp32
        #pragma unroll
        for (int j = t; j < 512; j += 256) {
            out[524296 + j] = ws[FB + 1288 + j];            // hn fp32
            out[524808 + j] = ws[FB + 1800 + j];            // cn fp32
        }
    }
}

// ============================================================================
extern "C" void kernel_launch(void* const* d_in, const int* in_sizes, int n_in,
                              void* d_out, int out_size, void* d_ws, size_t ws_size,
                              hipStream_t stream) {
    float* ws = (float*)d_ws;
    float* out = (float*)d_out;                 // output is fp32

    k12_main<<<dim3(264), dim3(256), 0, stream>>>(
        (const float*)d_in[0], (const float*)d_in[1],
        (const float*)d_in[2], (const float*)d_in[3],
        (const float*)d_in[4], (const float*)d_in[5],
        (const float*)d_in[6], (const float*)d_in[7],
        (const float*)d_in[8], (const float*)d_in[9],
        (const float*)d_in[10], (const float*)d_in[11],
        (const float*)d_in[12], (const float*)d_in[13],
        (const float*)d_in[14], (const float*)d_in[15],
        (const float*)d_in[16], (const float*)d_in[17],
        (const float*)d_in[18], (const float*)d_in[19], ws);
    k3_adv  <<<dim3(1024), dim3(256), 0, stream>>>(ws, (const float*)d_in[18], out);
}